// Round 11
// baseline (717.986 us; speedup 1.0000x reference)
//
#include <hip/hip_runtime.h>
#include <hip/hip_bf16.h>

static constexpr int Bn = 8, Dn = 512, Hn = 64, Wn = 64, Kn = 1024;
static constexpr int HW = Hn * Wn;            // 4096
static constexpr int NPIX = Bn * HW;          // 32768
static constexpr size_t OFF_LOSS = (size_t)Bn * Dn * HW;          // 16777216
static constexpr size_t OFF_PROB = OFF_LOSS + 1;                   // 16777217
static constexpr size_t OFF_IDX  = OFF_PROB + (size_t)NPIX * Kn;   // 50331649
static constexpr size_t OFF_PPRB = OFF_IDX + NPIX;                 // 50364417

typedef __attribute__((ext_vector_type(8))) short short8v;
typedef __attribute__((ext_vector_type(4))) float f32x4;
typedef unsigned long long ull;

// workspace layout (bytes)
static constexpr size_t WS_CB2   = 0;         // 1024 f32
static constexpr size_t WS_XXZ   = 4096;      // 32768 f32
static constexpr size_t WS_WIDX  = 135168;    // 32768 i32
static constexpr size_t WS_PART  = 266240;    // 4096 f32
static constexpr size_t WS_CBBF  = 282624;    // 1024*512 bf16 (1 MB)
static constexpr size_t WS_ABF   = 1331200;   // optional 64 MiB A-bf16 scratch
static constexpr size_t ABF_BYTES = (size_t)2 * NPIX * Dn * 2;  // 67108864

#define MARGIN 1e-3f

__device__ inline unsigned short f2bf(float x) {
  unsigned u = __float_as_uint(x);
  u += 0x7fffu + ((u >> 16) & 1u);  // RNE
  return (unsigned short)(u >> 16);
}
__device__ inline unsigned pack2(float a, float b) {
  return (unsigned)f2bf(a) | ((unsigned)f2bf(b) << 16);
}

__device__ inline void gload_lds16(const void* g, void* l) {
  __builtin_amdgcn_global_load_lds((const __attribute__((address_space(1))) void*)g,
                                   (__attribute__((address_space(3))) void*)l, 16, 0, 0);
}

// ---- numpy pairwise-sum replica for n=512 f32 row of squares ----
__device__ float np_pairwise_sq512(const float* __restrict__ base, int stride) {
  float B[4];
#pragma unroll
  for (int blk = 0; blk < 4; blk++) {
    const float* a = base + (size_t)blk * 128 * stride;
    float r[8][4];
#pragma unroll
    for (int k = 0; k < 8; k++)
#pragma unroll
      for (int j = 0; j < 4; j++) {
        float x = a[(size_t)(4 * k + j) * stride];
        r[k][j] = __fmul_rn(x, x);
      }
#pragma unroll
    for (int i = 32; i < 128; i += 32)
#pragma unroll
      for (int k = 0; k < 8; k++)
#pragma unroll
        for (int j = 0; j < 4; j++) {
          float x = a[(size_t)(i + 4 * k + j) * stride];
          r[k][j] = __fadd_rn(r[k][j], __fmul_rn(x, x));
        }
    float L[4];
#pragma unroll
    for (int j = 0; j < 4; j++) {
      float t01 = __fadd_rn(r[0][j], r[1][j]);
      float t23 = __fadd_rn(r[2][j], r[3][j]);
      float t45 = __fadd_rn(r[4][j], r[5][j]);
      float t67 = __fadd_rn(r[6][j], r[7][j]);
      L[j] = __fadd_rn(__fadd_rn(t01, t23), __fadd_rn(t45, t67));
    }
    B[blk] = __fadd_rn(__fadd_rn(L[0], L[1]), __fadd_rn(L[2], L[3]));
  }
  return __fadd_rn(__fadd_rn(B[0], B[1]), __fadd_rn(B[2], B[3]));
}

// ---------------- K0: CB->bf16, A transpose->bf16 scratch, norms ----------
__global__ __launch_bounds__(256) void k_init(const float* __restrict__ Z,
                                              const float* __restrict__ ZP,
                                              const float* __restrict__ CB,
                                              unsigned short* __restrict__ CBbf,
                                              unsigned short* __restrict__ Abf,
                                              float* __restrict__ xxZ,
                                              float* __restrict__ cb2) {
  int gid = blockIdx.x * 256 + threadIdx.x;
  {
    float2 f = *(const float2*)(CB + (size_t)gid * 2);
    union { __hip_bfloat162 h; unsigned u; } cv;
    cv.h = __float22bfloat162_rn(f);
    ((unsigned*)CBbf)[gid] = cv.u;
  }
  if (gid < 2 * NPIX) {
    const int p = gid & (NPIX - 1);
    const bool isz = gid < NPIX;
    const float* src = (isz ? Z : ZP) + (size_t)(p >> 12) * (Dn * HW) + (p & 4095);
    unsigned short* dst = Abf + (size_t)gid * Dn;
    float Bb[4];
#pragma unroll
    for (int blk = 0; blk < 4; blk++) {
      float rr[32];
#pragma unroll
      for (int i = 0; i < 128; i += 32) {
        float v[32];
#pragma unroll
        for (int t = 0; t < 32; t++) v[t] = src[(size_t)(blk * 128 + i + t) * HW];
        uint4 ua;
        unsigned* uw = (unsigned*)&ua;
#pragma unroll
        for (int q = 0; q < 4; q++) {
#pragma unroll
          for (int e = 0; e < 4; e++) uw[e] = pack2(v[q * 8 + 2 * e], v[q * 8 + 2 * e + 1]);
          *(uint4*)&dst[blk * 128 + i + q * 8] = ua;
        }
        if (isz) {
          if (i == 0) {
#pragma unroll
            for (int t = 0; t < 32; t++) rr[t] = __fmul_rn(v[t], v[t]);
          } else {
#pragma unroll
            for (int t = 0; t < 32; t++) rr[t] = __fadd_rn(rr[t], __fmul_rn(v[t], v[t]));
          }
        }
      }
      if (isz) {
        float L[4];
#pragma unroll
        for (int j = 0; j < 4; j++) {
          float t01 = __fadd_rn(rr[0 + j], rr[4 + j]);
          float t23 = __fadd_rn(rr[8 + j], rr[12 + j]);
          float t45 = __fadd_rn(rr[16 + j], rr[20 + j]);
          float t67 = __fadd_rn(rr[24 + j], rr[28 + j]);
          L[j] = __fadd_rn(__fadd_rn(t01, t23), __fadd_rn(t45, t67));
        }
        Bb[blk] = __fadd_rn(__fadd_rn(L[0], L[1]), __fadd_rn(L[2], L[3]));
      }
    }
    if (isz)
      xxZ[p] = __fadd_rn(__fadd_rn(Bb[0], Bb[1]), __fadd_rn(Bb[2], Bb[3]));
  } else if (gid < 2 * NPIX + Kn) {
    int k = gid - 2 * NPIX;
    cb2[k] = np_pairwise_sq512(CB + (size_t)k * Dn, 1);
  }
}

// ---------------- K1: fused 2-pass GEMM + softmax + argmin + refine --------
// grid 1024 (512 p-blocks x 2 mats), block 256 (4 waves, 2m x 2n).
// Block: 64 pixels x full K=1024. A LDS-resident; B staged per 32-c step.
// Pass 1: stats only (v1,i1,v2,expsum). Pass 2: identical MFMA recompute ->
// probs store + inline exact-f32 refine of in-margin candidates.
__global__ __launch_bounds__(256) void k_fused(const unsigned short* __restrict__ Abf,
                                               const unsigned short* __restrict__ CBbf,
                                               const float* __restrict__ CB,
                                               const float* __restrict__ Z,
                                               const float* __restrict__ cb2,
                                               const float* __restrict__ xxZ,
                                               float* __restrict__ out,
                                               int* __restrict__ widx) {
  __shared__ __align__(16) unsigned short Alds[64 * 512];   // 64 KB
  __shared__ __align__(16) unsigned short Bt[128 * 32];     // 8 KB
  __shared__ float rs_v1[4][32];
  __shared__ int   rs_i1[4][32];
  __shared__ float rs_v2[4][32];
  __shared__ float rs_sum[4][32];
  __shared__ float rf_thr[64];
  __shared__ float rf_inv[64];
  __shared__ int   rf_i1[64];
  __shared__ float rw_bd[4][32];
  __shared__ int   rw_bi[4][32];

  const int bid = blockIdx.x;
  const int zz = bid >> 9;
  const int p0 = (bid & 511) * 64;
  const unsigned short* Asrc = Abf + (size_t)(zz * NPIX + p0) * Dn;
  float* S = out + (zz ? OFF_PPRB : OFF_PROB);
  const int tid = threadIdx.x;
  const int lane = tid & 63, w = tid >> 6;
  const int fr = lane & 15, fg = lane >> 4;
  const int wm = w & 1, wn = w >> 1;
  const int r7 = fr & 7;
  const int swz = (fr >> 1) & 3;

  // ---- stage A once: 64 rows x 64 chunks(16B); LDS chunk cl holds source
  // chunk cl ^ (row&7) so MFMA reads are bank-spread ----
#pragma unroll
  for (int it = 0; it < 16; it++) {
    const int row = it * 4 + w;                // wave-uniform
    const int cs = lane ^ (row & 7);           // per-lane source chunk
    gload_lds16(Asrc + (size_t)row * Dn + cs * 8, &Alds[row * 512]);
  }
  __syncthreads();

  float v1a[8], v2a[8], suma[8]; int i1a[8];
  float thr8[8], inv8[8], bd8[8]; int bi8[8];

  for (int pass = 0; pass < 2; pass++) {
    if (pass == 0) {
#pragma unroll
      for (int t = 0; t < 8; t++) {
        v1a[t] = 1e30f; v2a[t] = 1e30f; suma[t] = 0.f; i1a[t] = 0x7fffffff;
      }
    } else {
#pragma unroll
      for (int m = 0; m < 2; m++)
#pragma unroll
        for (int r = 0; r < 4; r++) {
          const int row = wm * 32 + m * 16 + fg * 4 + r;
          thr8[m * 4 + r] = rf_thr[row];
          inv8[m * 4 + r] = rf_inv[row];
          bd8[m * 4 + r] = 1e30f; bi8[m * 4 + r] = 0x7fffffff;
        }
    }

    for (int j = 0; j < 8; j++) {
      const int k0 = j * 128;
      f32x4 acc[2][4] = {};
#pragma unroll
      for (int s = 0; s < 16; s++) {
        __syncthreads();   // all waves done reading Bt
#pragma unroll
        for (int h = 0; h < 2; h++) {
          const int G = tid + h * 256;
          const int row = G >> 2, g = G & 3;
          const int gsrc = g ^ ((row >> 1) & 3);
          const int ldsbase = ((tid & 192) + h * 256) * 8;  // wave-uniform
          gload_lds16(CBbf + (size_t)(k0 + row) * Dn + s * 32 + gsrc * 8, &Bt[ldsbase]);
        }
        __syncthreads();   // staged data visible (vmcnt drained by barrier)
        short8v af[2], bf[4];
#pragma unroll
        for (int m = 0; m < 2; m++) {
          const int row = wm * 32 + m * 16 + fr;
          af[m] = *(const short8v*)&Alds[row * 512 + (((s * 4 + fg) ^ r7) << 3)];
        }
#pragma unroll
        for (int n = 0; n < 4; n++)
          bf[n] = *(const short8v*)&Bt[(wn * 64 + n * 16 + fr) * 32 + ((fg ^ swz) * 8)];
#pragma unroll
        for (int m = 0; m < 2; m++)
#pragma unroll
          for (int n = 0; n < 4; n++)
            acc[m][n] = __builtin_amdgcn_mfma_f32_16x16x32_bf16(af[m], bf[n], acc[m][n], 0, 0, 0);
      }

      // ---- tile epilogue (s = cb2 - 2*m; identical expression both passes) ----
      float c2t[4];
#pragma unroll
      for (int n = 0; n < 4; n++) c2t[n] = cb2[k0 + wn * 64 + n * 16 + fr];

      if (pass == 0) {
#pragma unroll
        for (int m = 0; m < 2; m++)
#pragma unroll
          for (int r = 0; r < 4; r++) {
            const int slot = m * 4 + r;
#pragma unroll
            for (int n = 0; n < 4; n++) {
              float sv = __fsub_rn(c2t[n], __fmul_rn(2.0f, acc[m][n][r]));
              int k = k0 + wn * 64 + n * 16 + fr;
              suma[slot] += __expf(-sv);
              if (sv < v1a[slot]) { v2a[slot] = v1a[slot]; v1a[slot] = sv; i1a[slot] = k; }
              else if (sv < v2a[slot]) v2a[slot] = sv;
            }
          }
      } else {
#pragma unroll
        for (int m = 0; m < 2; m++)
#pragma unroll
          for (int r = 0; r < 4; r++) {
            const int slot = m * 4 + r;
            const int row = wm * 32 + m * 16 + fg * 4 + r;
            float* Sp = S + (size_t)(p0 + row) * Kn + k0 + wn * 64 + fr;
#pragma unroll
            for (int n = 0; n < 4; n++) {
              float sv = __fsub_rn(c2t[n], __fmul_rn(2.0f, acc[m][n][r]));
              Sp[n * 16] = __expf(-sv) * inv8[slot];
              ull mask = __ballot(sv <= thr8[slot]);
              while (mask) {
                int l = __ffsll(mask) - 1;
                mask &= mask - 1;
                const int kc = k0 + wn * 64 + n * 16 + (l & 15);
                const int rowl = wm * 32 + m * 16 + ((l >> 4) << 2) + r;
                const int p = p0 + rowl;
                const float* zcol = Z + (size_t)(p >> 12) * (Dn * HW) + (p & 4095);
                const float* cr = CB + (size_t)kc * Dn;
                float part = 0.f;
#pragma unroll
                for (int q = 0; q < 8; q++)
                  part = fmaf(zcol[(size_t)(lane + 64 * q) * HW], cr[lane + 64 * q], part);
#pragma unroll
                for (int d = 1; d < 64; d <<= 1) part += __shfl_xor(part, d, 64);
                float dd = __fsub_rn(__fadd_rn(xxZ[p], cb2[kc]), __fmul_rn(2.0f, part));
                if ((l >> 4) == fg) {  // lanes owning rowl in this slot
                  if (dd < bd8[slot] || (dd == bd8[slot] && kc < bi8[slot])) {
                    bd8[slot] = dd; bi8[slot] = kc;
                  }
                }
              }
            }
          }
      }
    }

    // ---- pass-end merges ----
    if (pass == 0) {
#pragma unroll
      for (int m = 0; m < 2; m++)
#pragma unroll
        for (int r = 0; r < 4; r++) {
          const int slot = m * 4 + r;
          float v1 = v1a[slot], v2 = v2a[slot], sm = suma[slot];
          int i1 = i1a[slot];
#pragma unroll
          for (int d = 1; d < 16; d <<= 1) {
            float ov1 = __shfl_xor(v1, d, 64);
            int oi1 = __shfl_xor(i1, d, 64);
            float ov2 = __shfl_xor(v2, d, 64);
            float os = __shfl_xor(sm, d, 64);
            sm += os;
            float lose;
            if (ov1 < v1 || (ov1 == v1 && oi1 < i1)) { lose = v1; v1 = ov1; i1 = oi1; }
            else lose = ov1;
            v2 = fminf(fminf(v2, ov2), lose);
          }
          if (fr == 0) {
            const int rowl = m * 16 + fg * 4 + r;
            rs_v1[w][rowl] = v1; rs_i1[w][rowl] = i1;
            rs_v2[w][rowl] = v2; rs_sum[w][rowl] = sm;
          }
        }
      __syncthreads();
      if (tid < 64) {
        const int row = tid, wmr = row >> 5, rowl = row & 31;
        float v1 = rs_v1[wmr][rowl]; int i1 = rs_i1[wmr][rowl];
        float v2 = rs_v2[wmr][rowl]; float sm = rs_sum[wmr][rowl];
        float ov1 = rs_v1[wmr + 2][rowl]; int oi1 = rs_i1[wmr + 2][rowl];
        float ov2 = rs_v2[wmr + 2][rowl];
        sm += rs_sum[wmr + 2][rowl];
        float lose;
        if (ov1 < v1 || (ov1 == v1 && oi1 < i1)) { lose = v1; v1 = ov1; i1 = oi1; }
        else lose = ov1;
        v2 = fminf(fminf(v2, ov2), lose);
        rf_inv[row] = 1.0f / sm;
        rf_i1[row] = i1;
        rf_thr[row] = (zz == 0 && v2 <= v1 + MARGIN) ? (v1 + MARGIN) : -1e30f;
      }
      __syncthreads();
    } else {
#pragma unroll
      for (int m = 0; m < 2; m++)
#pragma unroll
        for (int r = 0; r < 4; r++) {
          const int slot = m * 4 + r;
          float bd = bd8[slot]; int bi = bi8[slot];
#pragma unroll
          for (int d = 1; d < 16; d <<= 1) {
            float od = __shfl_xor(bd, d, 64);
            int oi = __shfl_xor(bi, d, 64);
            if (od < bd || (od == bd && oi < bi)) { bd = od; bi = oi; }
          }
          if (fr == 0) {
            const int rowl = m * 16 + fg * 4 + r;
            rw_bd[w][rowl] = bd; rw_bi[w][rowl] = bi;
          }
        }
      __syncthreads();
      if (zz == 0 && tid < 64) {
        const int row = tid, wmr = row >> 5, rowl = row & 31;
        float bd = rw_bd[wmr][rowl]; int bi = rw_bi[wmr][rowl];
        float od = rw_bd[wmr + 2][rowl]; int oi = rw_bi[wmr + 2][rowl];
        if (od < bd || (od == bd && oi < bi)) { bd = od; bi = oi; }
        const int fin = (bi != 0x7fffffff) ? bi : rf_i1[row];
        widx[p0 + row] = fin;
        out[OFF_IDX + p0 + row] = (float)fin;
      }
    }
  }
}

// ---------------- K2: z_q gather + squared-error partials ----------------
__global__ __launch_bounds__(256) void k_zqloss(const float* __restrict__ Z,
                                                const float* __restrict__ CB,
                                                const int* __restrict__ widx,
                                                float* __restrict__ out,
                                                float* __restrict__ partial) {
  __shared__ float red[256];
  const int t = threadIdx.x;
  float ls = 0.f;
  const size_t base = (size_t)blockIdx.x * 4096;
#pragma unroll
  for (int i = 0; i < 16; i++) {
    size_t e = base + (size_t)i * 256 + t;
    int hw = (int)(e & 4095);
    int c = (int)((e >> 12) & 511);
    int bb = (int)(e >> 21);
    int p = (bb << 12) | hw;
    float zv = Z[e];
    float qv = CB[(size_t)widx[p] * Dn + c];
    out[e] = qv;
    float d = zv - qv;
    ls = fmaf(d, d, ls);
  }
  red[t] = ls;
  __syncthreads();
  for (int s = 128; s > 0; s >>= 1) {
    if (t < s) red[t] += red[t + s];
    __syncthreads();
  }
  if (t == 0) partial[blockIdx.x] = red[0];
}

// ---------------- K3: finalize q_loss ----------------
__global__ __launch_bounds__(256) void k_loss(const float* __restrict__ partial,
                                              float* __restrict__ out) {
  __shared__ float red[256];
  const int t = threadIdx.x;
  float s = 0.f;
  for (int i = t; i < 4096; i += 256) s += partial[i];
  red[t] = s;
  __syncthreads();
  for (int k = 128; k > 0; k >>= 1) {
    if (t < k) red[t] += red[t + k];
    __syncthreads();
  }
  if (t == 0) out[OFF_LOSS] = red[0] * (1.25f / 16777216.0f);
}

extern "C" void kernel_launch(void* const* d_in, const int* in_sizes, int n_in,
                              void* d_out, int out_size, void* d_ws, size_t ws_size,
                              hipStream_t stream) {
  const float* Z = (const float*)d_in[0];
  const float* ZP = (const float*)d_in[1];
  const float* CB = (const float*)d_in[2];
  float* out = (float*)d_out;
  char* ws = (char*)d_ws;
  float* cb2 = (float*)(ws + WS_CB2);
  float* xxZ = (float*)(ws + WS_XXZ);
  int* widx = (int*)(ws + WS_WIDX);
  float* partial = (float*)(ws + WS_PART);
  unsigned short* CBbf = (unsigned short*)(ws + WS_CBBF);
  // A-bf16 scratch: prefer d_ws; else z_q out-region (fully rewritten by
  // k_zqloss each call; choice deterministic since ws_size is constant).
  unsigned short* Abf = (ws_size >= WS_ABF + ABF_BYTES)
                            ? (unsigned short*)(ws + WS_ABF)
                            : (unsigned short*)d_out;

  k_init<<<dim3(1024), 256, 0, stream>>>(Z, ZP, CB, CBbf, Abf, xxZ, cb2);
  k_fused<<<dim3(1024), 256, 0, stream>>>(Abf, CBbf, CB, Z, cb2, xxZ, out, widx);
  k_zqloss<<<dim3(4096), 256, 0, stream>>>(Z, CB, widx, out, partial);
  k_loss<<<dim3(1), 256, 0, stream>>>(partial, out);
}

// Round 12
// 539.589 us; speedup vs baseline: 1.3306x; 1.3306x over previous
//
#include <hip/hip_runtime.h>
#include <hip/hip_bf16.h>

static constexpr int Bn = 8, Dn = 512, Hn = 64, Wn = 64, Kn = 1024;
static constexpr int HW = Hn * Wn;            // 4096
static constexpr int NPIX = Bn * HW;          // 32768
static constexpr size_t OFF_LOSS = (size_t)Bn * Dn * HW;          // 16777216
static constexpr size_t OFF_PROB = OFF_LOSS + 1;                   // 16777217
static constexpr size_t OFF_IDX  = OFF_PROB + (size_t)NPIX * Kn;   // 50331649
static constexpr size_t OFF_PPRB = OFF_IDX + NPIX;                 // 50364417

typedef __attribute__((ext_vector_type(8))) short short8v;
typedef __attribute__((ext_vector_type(4))) float f32x4;
typedef unsigned long long ull;

// workspace layout (bytes)
static constexpr size_t WS_CB2   = 0;         // 1024 f32
static constexpr size_t WS_XXZ   = 4096;      // 32768 f32
static constexpr size_t WS_WIDX  = 135168;    // 32768 i32
static constexpr size_t WS_PART  = 266240;    // 4096 f32
static constexpr size_t WS_CBBF  = 282624;    // 1024*512 bf16 (1 MB)
static constexpr size_t WS_ABF   = 1331200;   // optional 64 MiB A-bf16 scratch
static constexpr size_t ABF_BYTES = (size_t)2 * NPIX * Dn * 2;  // 67108864

#define MARGIN 1e-3f

__device__ inline unsigned short f2bf(float x) {
  unsigned u = __float_as_uint(x);
  u += 0x7fffu + ((u >> 16) & 1u);  // RNE
  return (unsigned short)(u >> 16);
}
__device__ inline unsigned pack2(float a, float b) {
  return (unsigned)f2bf(a) | ((unsigned)f2bf(b) << 16);
}

__device__ inline void gload_lds16(const void* g, void* l) {
  __builtin_amdgcn_global_load_lds((const __attribute__((address_space(1))) void*)g,
                                   (__attribute__((address_space(3))) void*)l, 16, 0, 0);
}

// ---- numpy pairwise-sum replica for n=512 f32 row of squares ----
__device__ float np_pairwise_sq512(const float* __restrict__ base, int stride) {
  float B[4];
#pragma unroll
  for (int blk = 0; blk < 4; blk++) {
    const float* a = base + (size_t)blk * 128 * stride;
    float r[8][4];
#pragma unroll
    for (int k = 0; k < 8; k++)
#pragma unroll
      for (int j = 0; j < 4; j++) {
        float x = a[(size_t)(4 * k + j) * stride];
        r[k][j] = __fmul_rn(x, x);
      }
#pragma unroll
    for (int i = 32; i < 128; i += 32)
#pragma unroll
      for (int k = 0; k < 8; k++)
#pragma unroll
        for (int j = 0; j < 4; j++) {
          float x = a[(size_t)(i + 4 * k + j) * stride];
          r[k][j] = __fadd_rn(r[k][j], __fmul_rn(x, x));
        }
    float L[4];
#pragma unroll
    for (int j = 0; j < 4; j++) {
      float t01 = __fadd_rn(r[0][j], r[1][j]);
      float t23 = __fadd_rn(r[2][j], r[3][j]);
      float t45 = __fadd_rn(r[4][j], r[5][j]);
      float t67 = __fadd_rn(r[6][j], r[7][j]);
      L[j] = __fadd_rn(__fadd_rn(t01, t23), __fadd_rn(t45, t67));
    }
    B[blk] = __fadd_rn(__fadd_rn(L[0], L[1]), __fadd_rn(L[2], L[3]));
  }
  return __fadd_rn(__fadd_rn(B[0], B[1]), __fadd_rn(B[2], B[3]));
}

// ---------------- K0: CB->bf16, A transpose->bf16 scratch, norms ----------
__global__ __launch_bounds__(256) void k_init(const float* __restrict__ Z,
                                              const float* __restrict__ ZP,
                                              const float* __restrict__ CB,
                                              unsigned short* __restrict__ CBbf,
                                              unsigned short* __restrict__ Abf,
                                              float* __restrict__ xxZ,
                                              float* __restrict__ cb2) {
  int gid = blockIdx.x * 256 + threadIdx.x;
  {
    float2 f = *(const float2*)(CB + (size_t)gid * 2);
    union { __hip_bfloat162 h; unsigned u; } cv;
    cv.h = __float22bfloat162_rn(f);
    ((unsigned*)CBbf)[gid] = cv.u;
  }
  if (gid < 2 * NPIX) {
    const int p = gid & (NPIX - 1);
    const bool isz = gid < NPIX;
    const float* src = (isz ? Z : ZP) + (size_t)(p >> 12) * (Dn * HW) + (p & 4095);
    unsigned short* dst = Abf + (size_t)gid * Dn;
    float Bb[4];
#pragma unroll
    for (int blk = 0; blk < 4; blk++) {
      float rr[32];
#pragma unroll
      for (int i = 0; i < 128; i += 32) {
        float v[32];
#pragma unroll
        for (int t = 0; t < 32; t++) v[t] = src[(size_t)(blk * 128 + i + t) * HW];
        uint4 ua;
        unsigned* uw = (unsigned*)&ua;
#pragma unroll
        for (int q = 0; q < 4; q++) {
#pragma unroll
          for (int e = 0; e < 4; e++) uw[e] = pack2(v[q * 8 + 2 * e], v[q * 8 + 2 * e + 1]);
          *(uint4*)&dst[blk * 128 + i + q * 8] = ua;
        }
        if (isz) {
          if (i == 0) {
#pragma unroll
            for (int t = 0; t < 32; t++) rr[t] = __fmul_rn(v[t], v[t]);
          } else {
#pragma unroll
            for (int t = 0; t < 32; t++) rr[t] = __fadd_rn(rr[t], __fmul_rn(v[t], v[t]));
          }
        }
      }
      if (isz) {
        float L[4];
#pragma unroll
        for (int j = 0; j < 4; j++) {
          float t01 = __fadd_rn(rr[0 + j], rr[4 + j]);
          float t23 = __fadd_rn(rr[8 + j], rr[12 + j]);
          float t45 = __fadd_rn(rr[16 + j], rr[20 + j]);
          float t67 = __fadd_rn(rr[24 + j], rr[28 + j]);
          L[j] = __fadd_rn(__fadd_rn(t01, t23), __fadd_rn(t45, t67));
        }
        Bb[blk] = __fadd_rn(__fadd_rn(L[0], L[1]), __fadd_rn(L[2], L[3]));
      }
    }
    if (isz)
      xxZ[p] = __fadd_rn(__fadd_rn(Bb[0], Bb[1]), __fadd_rn(Bb[2], Bb[3]));
  } else if (gid < 2 * NPIX + Kn) {
    int k = gid - 2 * NPIX;
    cb2[k] = np_pairwise_sq512(CB + (size_t)k * Dn, 1);
  }
}

// ---------------- K1: fused GEMM(full K) + row softmax/argmin/refine ------
// grid 1024 (= 512 p-blocks x 2 mats), block 256 (4 waves, 2m x 2n).
// Block: 64 pixels x full K=1024, kx-loop of 8 tiles (round-10 inner loop),
// s written per tile; then one barrier and a k_row pass on L2-hot s.
__global__ __launch_bounds__(256) void k_fused(const unsigned short* __restrict__ Abf,
                                               const unsigned short* __restrict__ CBbf,
                                               const float* __restrict__ CB,
                                               const float* __restrict__ Z,
                                               const float* __restrict__ cb2,
                                               const float* __restrict__ xxZ,
                                               float* __restrict__ out,
                                               int* __restrict__ widx) {
  __shared__ __align__(16) unsigned short At[2][64 * 32];    // 4 KB each
  __shared__ __align__(16) unsigned short Bt[2][128 * 32];   // 8 KB each

  const int bid = blockIdx.x;
  const int zz = bid & 1;
  const int py = bid >> 1;
  const int p0 = py * 64;
  const unsigned short* Asrc = Abf + (size_t)(zz * NPIX + p0) * Dn;
  float* S = out + (zz ? OFF_PPRB : OFF_PROB);

  const int tid = threadIdx.x;
  const int lane = tid & 63, w = tid >> 6;
  const int fr = lane & 15, fg = lane >> 4;
  const int wm = w & 1, wn = w >> 1;
  const int swz = (fr >> 1) & 3;

  auto stage = [&](int buf, int t) {
    const int c0 = (t & 15) * 32;
    const int k0 = (t >> 4) * 128;
    {  // A: 64 rows x 32 c (one 16B chunk per thread)
      const int row = tid >> 2, g = tid & 3;
      const int gsrc = g ^ ((row >> 1) & 3);
      const int ldsbase = (tid & 192) * 8;  // wave-uniform
      gload_lds16(Asrc + (size_t)row * Dn + c0 + gsrc * 8, &At[buf][ldsbase]);
    }
#pragma unroll
    for (int h = 0; h < 2; h++) {  // B: 128 rows x 32 c
      const int G = tid + h * 256;
      const int row = G >> 2, g = G & 3;
      const int gsrc = g ^ ((row >> 1) & 3);
      const int ldsbase = ((tid & 192) + h * 256) * 8;  // wave-uniform
      gload_lds16(CBbf + (size_t)(k0 + row) * Dn + c0 + gsrc * 8, &Bt[buf][ldsbase]);
    }
  };

  stage(0, 0);
  int t = 0;
  for (int kx = 0; kx < 8; kx++) {
    const int k0 = kx * 128;
    f32x4 acc[2][4] = {};
#pragma unroll
    for (int s = 0; s < 16; s++, t++) {
      __syncthreads();
      if (t < 127) stage((t + 1) & 1, t + 1);
      const int cur = t & 1;
      short8v af[2], bf[4];
#pragma unroll
      for (int m = 0; m < 2; m++)
        af[m] = *(const short8v*)&At[cur][(wm * 32 + m * 16 + fr) * 32 + ((fg ^ swz) * 8)];
#pragma unroll
      for (int n = 0; n < 4; n++)
        bf[n] = *(const short8v*)&Bt[cur][(wn * 64 + n * 16 + fr) * 32 + ((fg ^ swz) * 8)];
#pragma unroll
      for (int m = 0; m < 2; m++)
#pragma unroll
        for (int n = 0; n < 4; n++)
          acc[m][n] = __builtin_amdgcn_mfma_f32_16x16x32_bf16(af[m], bf[n], acc[m][n], 0, 0, 0);
    }
    // tile epilogue: s = cb2[k] - 2*m (xx cancels; exact path in refine)
    float c2t[4];
#pragma unroll
    for (int n = 0; n < 4; n++) c2t[n] = cb2[k0 + wn * 64 + n * 16 + fr];
#pragma unroll
    for (int m = 0; m < 2; m++)
#pragma unroll
      for (int r = 0; r < 4; r++) {
        const int px = wm * 32 + m * 16 + fg * 4 + r;
        float* Sp = S + (size_t)(p0 + px) * Kn + k0 + wn * 64 + fr;
#pragma unroll
        for (int n = 0; n < 4; n++)
          Sp[n * 16] = __fsub_rn(c2t[n], __fmul_rn(2.0f, acc[m][n][r]));
      }
  }
  __syncthreads();  // s stores drained (vmcnt before barrier) -> L2-visible

  // ---- row pass on this block's L2-hot s (round-10 k_row, 16 rows/wave) ----
#pragma unroll 1
  for (int i = 0; i < 16; i++) {
    const int p = p0 + w * 16 + i;
    float* Sp = S + (size_t)p * Kn;
    float v[16];
#pragma unroll
    for (int jj = 0; jj < 16; jj++) v[jj] = Sp[jj * 64 + lane];

    float v1 = 1e30f, v2 = 1e30f, sum = 0.f;
    int i1 = 0x7fffffff;
#pragma unroll
    for (int jj = 0; jj < 16; jj++) {
      float x = v[jj];
      int k = jj * 64 + lane;
      sum += __expf(-x);
      if (x < v1) { v2 = v1; v1 = x; i1 = k; }
      else if (x < v2) { v2 = x; }
    }
#pragma unroll
    for (int d = 1; d < 64; d <<= 1) {
      float ov1 = __shfl_xor(v1, d, 64);
      int oi1 = __shfl_xor(i1, d, 64);
      float ov2 = __shfl_xor(v2, d, 64);
      float os = __shfl_xor(sum, d, 64);
      sum += os;
      float lose;
      if (ov1 < v1 || (ov1 == v1 && oi1 < i1)) { lose = v1; v1 = ov1; i1 = oi1; }
      else { lose = ov1; }
      v2 = fminf(fminf(v2, ov2), lose);
    }
    const float inv = 1.0f / sum;
    const float thr = v1 + MARGIN;

#pragma unroll
    for (int jj = 0; jj < 16; jj++) Sp[jj * 64 + lane] = __expf(-v[jj]) * inv;

    if (zz == 0) {
      int final_idx = i1;
      if (v2 <= thr) {
        // exact f32 refine, wave-parallel dot (round-10 proven; ulp(512)
        // quantization of d swamps dot-order differences)
        const float* zcol = Z + (size_t)(p >> 12) * (Dn * HW) + (p & 4095);
        float zc[8];
#pragma unroll
        for (int q = 0; q < 8; q++) zc[q] = zcol[(size_t)(lane + 64 * q) * HW];
        const float xx = xxZ[p];
        float bd = 1e30f;
        int bi = 0x7fffffff;
#pragma unroll
        for (int jj = 0; jj < 16; jj++) {
          ull mask = __ballot(v[jj] <= thr);
          while (mask) {
            int l = __ffsll(mask) - 1;
            mask &= mask - 1;
            int k = jj * 64 + l;          // ascending k across (jj, l)
            const float* cr = CB + (size_t)k * Dn;
            float part = 0.f;
#pragma unroll
            for (int q = 0; q < 8; q++) part = fmaf(zc[q], cr[lane + 64 * q], part);
#pragma unroll
            for (int d = 1; d < 64; d <<= 1) part += __shfl_xor(part, d, 64);
            float dd = __fsub_rn(__fadd_rn(xx, cb2[k]), __fmul_rn(2.0f, part));
            if (dd < bd) { bd = dd; bi = k; }  // strict <: lowest k wins ties
          }
        }
        final_idx = bi;
      }
      if (lane == 0) {
        widx[p] = final_idx;
        out[OFF_IDX + p] = (float)final_idx;
      }
    }
  }
}

// ---------------- K2: z_q gather + squared-error partials ----------------
__global__ __launch_bounds__(256) void k_zqloss(const float* __restrict__ Z,
                                                const float* __restrict__ CB,
                                                const int* __restrict__ widx,
                                                float* __restrict__ out,
                                                float* __restrict__ partial) {
  __shared__ float red[256];
  const int t = threadIdx.x;
  float ls = 0.f;
  const size_t base = (size_t)blockIdx.x * 4096;
#pragma unroll
  for (int i = 0; i < 16; i++) {
    size_t e = base + (size_t)i * 256 + t;
    int hw = (int)(e & 4095);
    int c = (int)((e >> 12) & 511);
    int bb = (int)(e >> 21);
    int p = (bb << 12) | hw;
    float zv = Z[e];
    float qv = CB[(size_t)widx[p] * Dn + c];
    out[e] = qv;
    float d = zv - qv;
    ls = fmaf(d, d, ls);
  }
  red[t] = ls;
  __syncthreads();
  for (int s = 128; s > 0; s >>= 1) {
    if (t < s) red[t] += red[t + s];
    __syncthreads();
  }
  if (t == 0) partial[blockIdx.x] = red[0];
}

// ---------------- K3: finalize q_loss ----------------
__global__ __launch_bounds__(256) void k_loss(const float* __restrict__ partial,
                                              float* __restrict__ out) {
  __shared__ float red[256];
  const int t = threadIdx.x;
  float s = 0.f;
  for (int i = t; i < 4096; i += 256) s += partial[i];
  red[t] = s;
  __syncthreads();
  for (int k = 128; k > 0; k >>= 1) {
    if (t < k) red[t] += red[t + k];
    __syncthreads();
  }
  if (t == 0) out[OFF_LOSS] = red[0] * (1.25f / 16777216.0f);
}

extern "C" void kernel_launch(void* const* d_in, const int* in_sizes, int n_in,
                              void* d_out, int out_size, void* d_ws, size_t ws_size,
                              hipStream_t stream) {
  const float* Z = (const float*)d_in[0];
  const float* ZP = (const float*)d_in[1];
  const float* CB = (const float*)d_in[2];
  float* out = (float*)d_out;
  char* ws = (char*)d_ws;
  float* cb2 = (float*)(ws + WS_CB2);
  float* xxZ = (float*)(ws + WS_XXZ);
  int* widx = (int*)(ws + WS_WIDX);
  float* partial = (float*)(ws + WS_PART);
  unsigned short* CBbf = (unsigned short*)(ws + WS_CBBF);
  unsigned short* Abf = (ws_size >= WS_ABF + ABF_BYTES)
                            ? (unsigned short*)(ws + WS_ABF)
                            : (unsigned short*)d_out;

  k_init<<<dim3(1024), 256, 0, stream>>>(Z, ZP, CB, CBbf, Abf, xxZ, cb2);
  k_fused<<<dim3(1024), 256, 0, stream>>>(Abf, CBbf, CB, Z, cb2, xxZ, out, widx);
  k_zqloss<<<dim3(4096), 256, 0, stream>>>(Z, CB, widx, out, partial);
  k_loss<<<dim3(1), 256, 0, stream>>>(partial, out);
}